// Round 11
// baseline (421.034 us; speedup 1.0000x reference)
//
#include <hip/hip_runtime.h>

#define N     16384
#define DH    64
#define TILE  128
#define NT    (N / TILE)

// pass2 tile geometry: 64 rows x 256 cols
#define TI    64
#define TJ    256
#define S2P   258   // padded fp32 stride for the P staging buffer

typedef __attribute__((ext_vector_type(8))) short  short8;
typedef __attribute__((ext_vector_type(4))) float  f32x4;

// ---- bf16 helpers (round-to-nearest-even) --------------------------------
__device__ __forceinline__ ushort bf_hi(float x) {
    unsigned u = __float_as_uint(x);
    unsigned r = u + 0x7FFFu + ((u >> 16) & 1u);
    return (ushort)(r >> 16);
}
__device__ __forceinline__ float bf_val(ushort h) {
    return __uint_as_float(((unsigned)h) << 16);
}

// per-lane 16B fragment load: 8 contiguous bf16 features of one h-row (global)
__device__ __forceinline__ short8 ldfrag(const ushort* __restrict__ p, int row, int koff) {
    return *(const short8*)(p + (size_t)row * DH + koff);
}

// ---------------------------------------------------------------------------
// Kernel 1: per-pedestrian MLP -> h split into bf16 hi/lo pair (hi+lo ~ fp32).
// ---------------------------------------------------------------------------
__global__ __launch_bounds__(128) void mlp_kernel(
    const float* __restrict__ data,
    const float* __restrict__ W1, const float* __restrict__ b1,
    const float* __restrict__ W2, const float* __restrict__ b2,
    const float* __restrict__ W3, const float* __restrict__ b3,
    ushort* __restrict__ hHi, ushort* __restrict__ hLo)
{
    __shared__ float sW1[64], sb1[32], sW2[32 * 64], sb2[64], sW3[64 * 64], sb3[64];
    const int tid = threadIdx.x;
    if (tid < 64) sW1[tid] = W1[tid];
    if (tid < 32) sb1[tid] = b1[tid];
    if (tid < 64) sb2[tid] = b2[tid];
    if (tid < 64) sb3[tid] = b3[tid];
    for (int t = tid; t < 32 * 64; t += 128) sW2[t] = W2[t];
    for (int t = tid; t < 64 * 64; t += 128) sW3[t] = W3[t];
    __syncthreads();

    const int i = blockIdx.x * 128 + tid;
    const float x0 = data[2 * i + 0];
    const float x1 = data[2 * i + 1];

    float h1[32];
#pragma unroll
    for (int o = 0; o < 32; ++o)
        h1[o] = fmaxf(0.f, fmaf(x0, sW1[o], fmaf(x1, sW1[32 + o], sb1[o])));

    float h2[64];
#pragma unroll
    for (int o = 0; o < 64; ++o) {
        float a = sb2[o];
#pragma unroll
        for (int k = 0; k < 32; ++k) a = fmaf(h1[k], sW2[k * 64 + o], a);
        h2[o] = fmaxf(0.f, a);
    }

    ushort hs[64], ls[64];
#pragma unroll
    for (int o = 0; o < 64; ++o) {
        float a = sb3[o];
#pragma unroll
        for (int k = 0; k < 64; ++k) a = fmaf(h2[k], sW3[k * 64 + o], a);
        const ushort hb = bf_hi(a);
        hs[o] = hb;
        ls[o] = bf_hi(a - bf_val(hb));
    }
#pragma unroll
    for (int q = 0; q < 8; ++q) {
        short8 vh, vl;
#pragma unroll
        for (int t = 0; t < 8; ++t) { vh[t] = (short)hs[q * 8 + t]; vl[t] = (short)ls[q * 8 + t]; }
        *(short8*)(hHi + (size_t)i * DH + q * 8) = vh;
        *(short8*)(hLo + (size_t)i * DH + q * 8) = vl;
    }
}

// ---------------------------------------------------------------------------
// B-tile staging into LDS with XOR chunk swizzle (conflict-free write+read).
// 128-row variant (pass1): sB[arr*8192 + row*64 + 8*(q^(row&7))]
// ---------------------------------------------------------------------------
__device__ __forceinline__ void stage_B(
    const ushort* __restrict__ hHi, const ushort* __restrict__ hLo,
    int brow0, int tid, ushort* __restrict__ sB)
{
    const int arr = tid >> 7;        // 0 = hi, 1 = lo
    const int r   = tid & 127;
    const ushort* __restrict__ src = (arr ? hLo : hHi) + (size_t)(brow0 + r) * DH;
    ushort* __restrict__ dst = sB + arr * (TILE * DH) + r * 64;
    const int sw = (r & 7);
#pragma unroll
    for (int q = 0; q < 8; ++q) {
        const short8 v = *(const short8*)(src + q * 8);
        *(short8*)(dst + 8 * (q ^ sw)) = v;
    }
}

__device__ __forceinline__ short8 ldB(const ushort* __restrict__ sB,
                                      int arr, int row, int ks, int kb)
{
    return *(const short8*)(sB + arr * (TILE * DH) + row * 64 + 8 * (((ks << 2) + kb) ^ (row & 7)));
}

// 256-row variant (pass2): hi rows at [row*64 + ...], lo at +16384 ushorts.
__device__ __forceinline__ void stage_B256(
    const ushort* __restrict__ hHi, const ushort* __restrict__ hLo,
    int brow0, int tid, ushort* __restrict__ sB)
{
    const int r = tid;               // 0..255
    const ushort* __restrict__ srcH = hHi + (size_t)(brow0 + r) * DH;
    const ushort* __restrict__ srcL = hLo + (size_t)(brow0 + r) * DH;
    ushort* __restrict__ dstH = sB + r * 64;
    ushort* __restrict__ dstL = sB + (TJ * DH) + r * 64;
    const int sw = (r & 7);
#pragma unroll
    for (int q = 0; q < 8; ++q) {
        const short8 vh = *(const short8*)(srcH + q * 8);
        const short8 vl = *(const short8*)(srcL + q * 8);
        *(short8*)(dstH + 8 * (q ^ sw)) = vh;
        *(short8*)(dstL + 8 * (q ^ sw)) = vl;
    }
}

__device__ __forceinline__ short8 ldB256(const ushort* __restrict__ sB,
                                         int arr, int row, int ks, int kb)
{
    return *(const short8*)(sB + arr * (TJ * DH) + row * 64 + 8 * (((ks << 2) + kb) ^ (row & 7)));
}

// ---------------------------------------------------------------------------
// Pass1 gram: 128x128 G-tile, 4 waves; wave w owns rows {w*16..+15} (rb=0)
// and {64+w*16..+15} (rb=1). ks hoisted for low A liveness.
// acc[rb][cb] 16x16 fragment; C layout: col = lane&15, row = (lane>>4)*4+reg.
// G = hiA*hiB + hiA*loB + loA*hiB  (lo*lo dropped, ~2^-18 relative).
// ---------------------------------------------------------------------------
__device__ __forceinline__ void gram_tile(
    const ushort* __restrict__ hHi, const ushort* __restrict__ hLo,
    const ushort* __restrict__ sB,
    int bi, int wave, int r16, int kb, f32x4 acc[2][8])
{
#pragma unroll
    for (int rb = 0; rb < 2; ++rb)
#pragma unroll
        for (int cb = 0; cb < 8; ++cb) acc[rb][cb] = (f32x4){0.f, 0.f, 0.f, 0.f};

    const int arow = bi * TILE + wave * 16 + r16;
#pragma unroll
    for (int ks = 0; ks < 2; ++ks) {
        const int koff = ks * 32 + kb * 8;
        const short8 Ah0 = ldfrag(hHi, arow,      koff);
        const short8 Ah1 = ldfrag(hHi, arow + 64, koff);
        const short8 Al0 = ldfrag(hLo, arow,      koff);
        const short8 Al1 = ldfrag(hLo, arow + 64, koff);
#pragma unroll
        for (int cb = 0; cb < 8; ++cb) {
            const int brow = cb * 16 + r16;
            const short8 Bh = ldB(sB, 0, brow, ks, kb);
            const short8 Bl = ldB(sB, 1, brow, ks, kb);
            acc[0][cb] = __builtin_amdgcn_mfma_f32_16x16x32_bf16(Ah0, Bh, acc[0][cb], 0, 0, 0);
            acc[0][cb] = __builtin_amdgcn_mfma_f32_16x16x32_bf16(Ah0, Bl, acc[0][cb], 0, 0, 0);
            acc[0][cb] = __builtin_amdgcn_mfma_f32_16x16x32_bf16(Al0, Bh, acc[0][cb], 0, 0, 0);
            acc[1][cb] = __builtin_amdgcn_mfma_f32_16x16x32_bf16(Ah1, Bh, acc[1][cb], 0, 0, 0);
            acc[1][cb] = __builtin_amdgcn_mfma_f32_16x16x32_bf16(Ah1, Bl, acc[1][cb], 0, 0, 0);
            acc[1][cb] = __builtin_amdgcn_mfma_f32_16x16x32_bf16(Al1, Bh, acc[1][cb], 0, 0, 0);
        }
    }
}

// thread's row within the pass1 tile for (rb, reg)
__device__ __forceinline__ int tile_row(int wave, int kb, int rb, int reg) {
    return rb * 64 + wave * 16 + kb * 4 + reg;
}

// triangle pair decode with balanced XCD banding: p -> (bi <= bj).
__device__ __forceinline__ void tri_decode(int p, int& bi, int& bj) {
    const int xcd = p & 7, s = p >> 3;        // s in [0, 1032)
    const int q = s / 129, r = s % 129;       // q in [0,8)
    const int P = xcd * 8 + q;                // pair id in [0,64)
    if (r <= P) { bi = r;         bj = P;       }
    else        { bi = r - P - 1; bj = 127 - P; }
}

#define SMEM1_BYTES 32768               // pass1: B stage (jm/jl alias inside)
#define SMEM2_BYTES (S2P * TI * 4)      // pass2: 66048 >= B stage 65536

// ---------------------------------------------------------------------------
// Kernel 2: symmetric pass 1 (triangle). Emits per-row (tile max, sum-exp)
// partials for both sides. Unchanged from R10.
// ---------------------------------------------------------------------------
__global__ __launch_bounds__(256, 4) void pass1_mfma(
    const ushort* __restrict__ hHi, const ushort* __restrict__ hLo,
    float* __restrict__ part_m, float* __restrict__ part_l)
{
    int bi, bj;
    tri_decode(blockIdx.x, bi, bj);

    __shared__ __attribute__((aligned(16))) char smem[SMEM1_BYTES];
    ushort* sB = (ushort*)smem;
    float*  jm = (float*)smem;            // aliases sB after compute
    float*  jl = jm + 512;                // [4][128] each

    const int tid = threadIdx.x;
    const int wave = tid >> 6, lane = tid & 63;
    const int r16 = lane & 15, kb = lane >> 4;

    stage_B(hHi, hLo, bj * TILE, tid, sB);
    __syncthreads();

    f32x4 acc[2][8];
    gram_tile(hHi, hLo, sB, bi, wave, r16, kb, acc);

    // ---- i-side: this thread's 8 rows over the 128 cols ----
#pragma unroll
    for (int rb = 0; rb < 2; ++rb) {
#pragma unroll
        for (int reg = 0; reg < 4; ++reg) {
            float m = acc[rb][0][reg];
#pragma unroll
            for (int cb = 1; cb < 8; ++cb) m = fmaxf(m, acc[rb][cb][reg]);
            m = fmaxf(m, __shfl_xor(m, 1));
            m = fmaxf(m, __shfl_xor(m, 2));
            m = fmaxf(m, __shfl_xor(m, 4));
            m = fmaxf(m, __shfl_xor(m, 8));
            float sum = 0.f;
#pragma unroll
            for (int cb = 0; cb < 8; ++cb) sum += __expf(acc[rb][cb][reg] - m);
            sum += __shfl_xor(sum, 1);
            sum += __shfl_xor(sum, 2);
            sum += __shfl_xor(sum, 4);
            sum += __shfl_xor(sum, 8);
            if (r16 == 0) {
                const int grow = bi * TILE + tile_row(wave, kb, rb, reg);
                part_m[(size_t)bj * N + grow] = m;
                part_l[(size_t)bj * N + grow] = sum;
            }
        }
    }

    // ---- j-side: tile columns over cols of tile bi ----
    if (bi != bj) {
        __syncthreads();   // all waves done reading sB; safe to alias jm/jl
#pragma unroll
        for (int cb = 0; cb < 8; ++cb) {
            float m = acc[0][cb][0];
#pragma unroll
            for (int rb = 0; rb < 2; ++rb)
#pragma unroll
                for (int reg = 0; reg < 4; ++reg) m = fmaxf(m, acc[rb][cb][reg]);
            m = fmaxf(m, __shfl_xor(m, 16));
            m = fmaxf(m, __shfl_xor(m, 32));
            float sum = 0.f;
#pragma unroll
            for (int rb = 0; rb < 2; ++rb)
#pragma unroll
                for (int reg = 0; reg < 4; ++reg) sum += __expf(acc[rb][cb][reg] - m);
            sum += __shfl_xor(sum, 16);
            sum += __shfl_xor(sum, 32);
            if (kb == 0) { jm[wave * 128 + cb * 16 + r16] = m; jl[wave * 128 + cb * 16 + r16] = sum; }
        }
        __syncthreads();
        if (tid < 128) {
            float M = jm[tid];
#pragma unroll
            for (int w = 1; w < 4; ++w) M = fmaxf(M, jm[w * 128 + tid]);
            float L = 0.f;
#pragma unroll
            for (int w = 0; w < 4; ++w) L += jl[w * 128 + tid] * __expf(jm[w * 128 + tid] - M);
            part_m[(size_t)bi * N + bj * TILE + tid] = M;
            part_l[(size_t)bi * N + bj * TILE + tid] = L;
        }
    }
}

// ---------------------------------------------------------------------------
// Kernel 3: merge 128 partial (m,l) per row -> rowmax m_i, r_i = 1/L.
// ---------------------------------------------------------------------------
__global__ __launch_bounds__(256) void merge_kernel(
    const float* __restrict__ part_m, const float* __restrict__ part_l,
    float* __restrict__ mrow, float* __restrict__ rrow)
{
    const int i = blockIdx.x * 256 + threadIdx.x;
    float M = -3.0e38f;
    for (int o = 0; o < NT; ++o) M = fmaxf(M, part_m[(size_t)o * N + i]);
    float L = 0.f;
    for (int o = 0; o < NT; ++o)
        L = fmaf(part_l[(size_t)o * N + i], __expf(part_m[(size_t)o * N + i] - M), L);
    mrow[i] = M;
    rrow[i] = 1.0f / L;
}

// ---------------------------------------------------------------------------
// Kernel 4: pass 2, 64x256 tiles. Wave w owns rows [bi*64 + w*16, +16), all
// 256 cols (16 col-fragments). Per-row store span = 1KB; each wave store
// instruction writes 1KB contiguous of ONE row (better DRAM page locality).
// XCD k owns bj-chunks [8k, 8k+8) (512KB B working set, L2-resident).
// ---------------------------------------------------------------------------
__global__ __launch_bounds__(256, 2) void pass2_mfma(
    const ushort* __restrict__ hHi, const ushort* __restrict__ hLo,
    const float* __restrict__ mrow, const float* __restrict__ rrow,
    float* __restrict__ out)
{
    const int p = blockIdx.x;
    const int xcd = p & 7, slot = p >> 3;          // slot in [0, 2048)
    const int bj = xcd * 8 + (slot & 7);           // [0, 64)
    const int bi = slot >> 3;                      // [0, 256)

    const int tid = threadIdx.x;
    const int wave = tid >> 6, lane = tid & 63;
    const int r16 = lane & 15, kb = lane >> 4;

    __shared__ __attribute__((aligned(16))) char smem[SMEM2_BYTES];
    ushort* sB   = (ushort*)smem;
    float*  ldsP = (float*)smem;   // aliases sB after compute

    stage_B256(hHi, hLo, bj * TJ, tid, sB);
    __syncthreads();

    // gram: 16 col-fragments, 1 row-fragment per wave
    f32x4 acc[16];
#pragma unroll
    for (int cb = 0; cb < 16; ++cb) acc[cb] = (f32x4){0.f, 0.f, 0.f, 0.f};

    const int arow = bi * TI + wave * 16 + r16;
#pragma unroll
    for (int ks = 0; ks < 2; ++ks) {
        const int koff = ks * 32 + kb * 8;
        const short8 Ah = ldfrag(hHi, arow, koff);
        const short8 Al = ldfrag(hLo, arow, koff);
#pragma unroll
        for (int cb = 0; cb < 16; ++cb) {
            const int brow = cb * 16 + r16;
            const short8 Bh = ldB256(sB, 0, brow, ks, kb);
            const short8 Bl = ldB256(sB, 1, brow, ks, kb);
            acc[cb] = __builtin_amdgcn_mfma_f32_16x16x32_bf16(Ah, Bh, acc[cb], 0, 0, 0);
            acc[cb] = __builtin_amdgcn_mfma_f32_16x16x32_bf16(Ah, Bl, acc[cb], 0, 0, 0);
            acc[cb] = __builtin_amdgcn_mfma_f32_16x16x32_bf16(Al, Bh, acc[cb], 0, 0, 0);
        }
    }
    __syncthreads();   // all waves done reading sB; safe to alias ldsP

    // epilogue: exp into LDS (row rl = wave*16 + kb*4 + reg)
#pragma unroll
    for (int reg = 0; reg < 4; ++reg) {
        const int rl   = wave * 16 + kb * 4 + reg;   // 0..63
        const int grow = bi * TI + rl;
        const float m  = mrow[grow];
        const float rr = rrow[grow];
#pragma unroll
        for (int cb = 0; cb < 16; ++cb)
            ldsP[rl * S2P + cb * 16 + r16] = __expf(acc[cb][reg] - m) * rr;
    }
    __syncthreads();

    // store: 4096 float4 = 64 rows x 64 float4; each wave-inst = 1KB of 1 row
#pragma unroll
    for (int qq = 0; qq < 16; ++qq) {
        const int f4 = tid + 256 * qq;
        const int rl = f4 >> 6, c4 = f4 & 63;
        const f32x4 v = *(const f32x4*)&ldsP[rl * S2P + c4 * 4];
        f32x4* dst = (f32x4*)(out + (size_t)(bi * TI + rl) * N + bj * TJ + c4 * 4);
        __builtin_nontemporal_store(v, dst);
    }
}

// ---------------------------------------------------------------------------
extern "C" void kernel_launch(void* const* d_in, const int* in_sizes, int n_in,
                              void* d_out, int out_size, void* d_ws, size_t ws_size,
                              hipStream_t stream)
{
    const float* data = (const float*)d_in[0];
    const float* W1   = (const float*)d_in[1];
    const float* b1   = (const float*)d_in[2];
    const float* W2   = (const float*)d_in[3];
    const float* b2   = (const float*)d_in[4];
    const float* W3   = (const float*)d_in[5];
    const float* b3   = (const float*)d_in[6];
    float* out = (float*)d_out;

    // workspace: part_m[NT*N] | part_l[NT*N] | mrow[N] | rrow[N] | hHi[N*64] | hLo[N*64]
    float* part_m = (float*)d_ws;
    float* part_l = part_m + (size_t)NT * N;
    float* mrow   = part_l + (size_t)NT * N;
    float* rrow   = mrow + N;
    ushort* hHi   = (ushort*)(rrow + N);
    ushort* hLo   = hHi + (size_t)N * DH;

    mlp_kernel<<<N / 128, 128, 0, stream>>>(data, W1, b1, W2, b2, W3, b3, hHi, hLo);
    pass1_mfma<<<NT * (NT + 1) / 2, 256, 0, stream>>>(hHi, hLo, part_m, part_l);
    merge_kernel<<<N / 256, 256, 0, stream>>>(part_m, part_l, mrow, rrow);
    pass2_mfma<<<(N / TI) * (N / TJ), 256, 0, stream>>>(hHi, hLo, mrow, rrow, out);
}

// Round 12
// 355.809 us; speedup vs baseline: 1.1833x; 1.1833x over previous
//
#include <hip/hip_runtime.h>

#define N     16384
#define DH    64
#define TILE  128
#define NT    (N / TILE)
#define S2    133   // padded LDS stride for the P-tile staging buffer

typedef __attribute__((ext_vector_type(8))) short  short8;
typedef __attribute__((ext_vector_type(4))) float  f32x4;

// ---- bf16 helpers (round-to-nearest-even) --------------------------------
__device__ __forceinline__ ushort bf_hi(float x) {
    unsigned u = __float_as_uint(x);
    unsigned r = u + 0x7FFFu + ((u >> 16) & 1u);
    return (ushort)(r >> 16);
}
__device__ __forceinline__ float bf_val(ushort h) {
    return __uint_as_float(((unsigned)h) << 16);
}

// per-lane 16B fragment load: 8 contiguous bf16 features of one h-row (global)
__device__ __forceinline__ short8 ldfrag(const ushort* __restrict__ p, int row, int koff) {
    return *(const short8*)(p + (size_t)row * DH + koff);
}

// ---------------------------------------------------------------------------
// Kernel 1: per-pedestrian MLP -> h split into bf16 hi/lo pair (hi+lo ~ fp32).
// ---------------------------------------------------------------------------
__global__ __launch_bounds__(128) void mlp_kernel(
    const float* __restrict__ data,
    const float* __restrict__ W1, const float* __restrict__ b1,
    const float* __restrict__ W2, const float* __restrict__ b2,
    const float* __restrict__ W3, const float* __restrict__ b3,
    ushort* __restrict__ hHi, ushort* __restrict__ hLo)
{
    __shared__ float sW1[64], sb1[32], sW2[32 * 64], sb2[64], sW3[64 * 64], sb3[64];
    const int tid = threadIdx.x;
    if (tid < 64) sW1[tid] = W1[tid];
    if (tid < 32) sb1[tid] = b1[tid];
    if (tid < 64) sb2[tid] = b2[tid];
    if (tid < 64) sb3[tid] = b3[tid];
    for (int t = tid; t < 32 * 64; t += 128) sW2[t] = W2[t];
    for (int t = tid; t < 64 * 64; t += 128) sW3[t] = W3[t];
    __syncthreads();

    const int i = blockIdx.x * 128 + tid;
    const float x0 = data[2 * i + 0];
    const float x1 = data[2 * i + 1];

    float h1[32];
#pragma unroll
    for (int o = 0; o < 32; ++o)
        h1[o] = fmaxf(0.f, fmaf(x0, sW1[o], fmaf(x1, sW1[32 + o], sb1[o])));

    float h2[64];
#pragma unroll
    for (int o = 0; o < 64; ++o) {
        float a = sb2[o];
#pragma unroll
        for (int k = 0; k < 32; ++k) a = fmaf(h1[k], sW2[k * 64 + o], a);
        h2[o] = fmaxf(0.f, a);
    }

    ushort hs[64], ls[64];
#pragma unroll
    for (int o = 0; o < 64; ++o) {
        float a = sb3[o];
#pragma unroll
        for (int k = 0; k < 64; ++k) a = fmaf(h2[k], sW3[k * 64 + o], a);
        const ushort hb = bf_hi(a);
        hs[o] = hb;
        ls[o] = bf_hi(a - bf_val(hb));
    }
#pragma unroll
    for (int q = 0; q < 8; ++q) {
        short8 vh, vl;
#pragma unroll
        for (int t = 0; t < 8; ++t) { vh[t] = (short)hs[q * 8 + t]; vl[t] = (short)ls[q * 8 + t]; }
        *(short8*)(hHi + (size_t)i * DH + q * 8) = vh;
        *(short8*)(hLo + (size_t)i * DH + q * 8) = vl;
    }
}

// ---------------------------------------------------------------------------
// B-tile staging into LDS with XOR chunk swizzle (conflict-free write+read).
// sB[arr*8192 + row*64 + 8*(q^(row&7))], q = ks*4+kb.
// ---------------------------------------------------------------------------
__device__ __forceinline__ void stage_B(
    const ushort* __restrict__ hHi, const ushort* __restrict__ hLo,
    int brow0, int tid, ushort* __restrict__ sB)
{
    const int arr = tid >> 7;        // 0 = hi, 1 = lo
    const int r   = tid & 127;
    const ushort* __restrict__ src = (arr ? hLo : hHi) + (size_t)(brow0 + r) * DH;
    ushort* __restrict__ dst = sB + arr * (TILE * DH) + r * 64;
    const int sw = (r & 7);
#pragma unroll
    for (int q = 0; q < 8; ++q) {
        const short8 v = *(const short8*)(src + q * 8);
        *(short8*)(dst + 8 * (q ^ sw)) = v;
    }
}

__device__ __forceinline__ short8 ldB(const ushort* __restrict__ sB,
                                      int arr, int row, int ks, int kb)
{
    return *(const short8*)(sB + arr * (TILE * DH) + row * 64 + 8 * (((ks << 2) + kb) ^ (row & 7)));
}

// ---------------------------------------------------------------------------
// Shared MFMA tile computation: 128x128 G-tile, 4 waves.
// Row ownership: wave w owns rows {w*16..+15} (rb=0) and {64+w*16..+15} (rb=1).
// ks hoisted for low A liveness. acc[rb][cb] 16x16 fragment;
// C layout: col = lane&15, row = (lane>>4)*4+reg.
// G = hiA*hiB + hiA*loB + loA*hiB  (lo*lo dropped, ~2^-18 relative).
// ---------------------------------------------------------------------------
__device__ __forceinline__ void gram_tile(
    const ushort* __restrict__ hHi, const ushort* __restrict__ hLo,
    const ushort* __restrict__ sB,
    int bi, int wave, int r16, int kb, f32x4 acc[2][8])
{
#pragma unroll
    for (int rb = 0; rb < 2; ++rb)
#pragma unroll
        for (int cb = 0; cb < 8; ++cb) acc[rb][cb] = (f32x4){0.f, 0.f, 0.f, 0.f};

    const int arow = bi * TILE + wave * 16 + r16;
#pragma unroll
    for (int ks = 0; ks < 2; ++ks) {
        const int koff = ks * 32 + kb * 8;
        const short8 Ah0 = ldfrag(hHi, arow,      koff);
        const short8 Ah1 = ldfrag(hHi, arow + 64, koff);
        const short8 Al0 = ldfrag(hLo, arow,      koff);
        const short8 Al1 = ldfrag(hLo, arow + 64, koff);
#pragma unroll
        for (int cb = 0; cb < 8; ++cb) {
            const int brow = cb * 16 + r16;
            const short8 Bh = ldB(sB, 0, brow, ks, kb);
            const short8 Bl = ldB(sB, 1, brow, ks, kb);
            acc[0][cb] = __builtin_amdgcn_mfma_f32_16x16x32_bf16(Ah0, Bh, acc[0][cb], 0, 0, 0);
            acc[0][cb] = __builtin_amdgcn_mfma_f32_16x16x32_bf16(Ah0, Bl, acc[0][cb], 0, 0, 0);
            acc[0][cb] = __builtin_amdgcn_mfma_f32_16x16x32_bf16(Al0, Bh, acc[0][cb], 0, 0, 0);
            acc[1][cb] = __builtin_amdgcn_mfma_f32_16x16x32_bf16(Ah1, Bh, acc[1][cb], 0, 0, 0);
            acc[1][cb] = __builtin_amdgcn_mfma_f32_16x16x32_bf16(Ah1, Bl, acc[1][cb], 0, 0, 0);
            acc[1][cb] = __builtin_amdgcn_mfma_f32_16x16x32_bf16(Al1, Bh, acc[1][cb], 0, 0, 0);
        }
    }
}

// thread's row within the pass1 tile for (rb, reg)
__device__ __forceinline__ int tile_row(int wave, int kb, int rb, int reg) {
    return rb * 64 + wave * 16 + kb * 4 + reg;
}

// triangle pair decode with balanced XCD banding: p -> (bi <= bj).
__device__ __forceinline__ void tri_decode(int p, int& bi, int& bj) {
    const int xcd = p & 7, s = p >> 3;        // s in [0, 1032)
    const int q = s / 129, r = s % 129;       // q in [0,8)
    const int P = xcd * 8 + q;                // pair id in [0,64)
    if (r <= P) { bi = r;         bj = P;       }
    else        { bi = r - P - 1; bj = 127 - P; }
}

#define SMEM1_BYTES 32768   // pass1: B stage (jm/jl alias inside)

// ---------------------------------------------------------------------------
// Kernel 2: symmetric pass 1 (triangle). Emits per-row (tile max, sum-exp)
// partials for both sides. Unchanged from R10.
// ---------------------------------------------------------------------------
__global__ __launch_bounds__(256, 4) void pass1_mfma(
    const ushort* __restrict__ hHi, const ushort* __restrict__ hLo,
    float* __restrict__ part_m, float* __restrict__ part_l)
{
    int bi, bj;
    tri_decode(blockIdx.x, bi, bj);

    __shared__ __attribute__((aligned(16))) char smem[SMEM1_BYTES];
    ushort* sB = (ushort*)smem;
    float*  jm = (float*)smem;            // aliases sB after compute
    float*  jl = jm + 512;                // [4][128] each

    const int tid = threadIdx.x;
    const int wave = tid >> 6, lane = tid & 63;
    const int r16 = lane & 15, kb = lane >> 4;

    stage_B(hHi, hLo, bj * TILE, tid, sB);
    __syncthreads();

    f32x4 acc[2][8];
    gram_tile(hHi, hLo, sB, bi, wave, r16, kb, acc);

    // ---- i-side: this thread's 8 rows over the 128 cols ----
#pragma unroll
    for (int rb = 0; rb < 2; ++rb) {
#pragma unroll
        for (int reg = 0; reg < 4; ++reg) {
            float m = acc[rb][0][reg];
#pragma unroll
            for (int cb = 1; cb < 8; ++cb) m = fmaxf(m, acc[rb][cb][reg]);
            m = fmaxf(m, __shfl_xor(m, 1));
            m = fmaxf(m, __shfl_xor(m, 2));
            m = fmaxf(m, __shfl_xor(m, 4));
            m = fmaxf(m, __shfl_xor(m, 8));
            float sum = 0.f;
#pragma unroll
            for (int cb = 0; cb < 8; ++cb) sum += __expf(acc[rb][cb][reg] - m);
            sum += __shfl_xor(sum, 1);
            sum += __shfl_xor(sum, 2);
            sum += __shfl_xor(sum, 4);
            sum += __shfl_xor(sum, 8);
            if (r16 == 0) {
                const int grow = bi * TILE + tile_row(wave, kb, rb, reg);
                part_m[(size_t)bj * N + grow] = m;
                part_l[(size_t)bj * N + grow] = sum;
            }
        }
    }

    // ---- j-side: tile columns over cols of tile bi ----
    if (bi != bj) {
        __syncthreads();   // all waves done reading sB; safe to alias jm/jl
#pragma unroll
        for (int cb = 0; cb < 8; ++cb) {
            float m = acc[0][cb][0];
#pragma unroll
            for (int rb = 0; rb < 2; ++rb)
#pragma unroll
                for (int reg = 0; reg < 4; ++reg) m = fmaxf(m, acc[rb][cb][reg]);
            m = fmaxf(m, __shfl_xor(m, 16));
            m = fmaxf(m, __shfl_xor(m, 32));
            float sum = 0.f;
#pragma unroll
            for (int rb = 0; rb < 2; ++rb)
#pragma unroll
                for (int reg = 0; reg < 4; ++reg) sum += __expf(acc[rb][cb][reg] - m);
            sum += __shfl_xor(sum, 16);
            sum += __shfl_xor(sum, 32);
            if (kb == 0) { jm[wave * 128 + cb * 16 + r16] = m; jl[wave * 128 + cb * 16 + r16] = sum; }
        }
        __syncthreads();
        if (tid < 128) {
            float M = jm[tid];
#pragma unroll
            for (int w = 1; w < 4; ++w) M = fmaxf(M, jm[w * 128 + tid]);
            float L = 0.f;
#pragma unroll
            for (int w = 0; w < 4; ++w) L += jl[w * 128 + tid] * __expf(jm[w * 128 + tid] - M);
            part_m[(size_t)bi * N + bj * TILE + tid] = M;
            part_l[(size_t)bi * N + bj * TILE + tid] = L;
        }
    }
}

// ---------------------------------------------------------------------------
// Kernel 3: merge 128 partial (m,l) per row -> fused srow = m + ln(L).
// pass2 then computes P = exp(g - srow): one stat load, no multiply.
// ---------------------------------------------------------------------------
__global__ __launch_bounds__(256) void merge_kernel(
    const float* __restrict__ part_m, const float* __restrict__ part_l,
    float* __restrict__ srow)
{
    const int i = blockIdx.x * 256 + threadIdx.x;
    float M = -3.0e38f;
    for (int o = 0; o < NT; ++o) M = fmaxf(M, part_m[(size_t)o * N + i]);
    float L = 0.f;
    for (int o = 0; o < NT; ++o)
        L = fmaf(part_l[(size_t)o * N + i], __expf(part_m[(size_t)o * N + i] - M), L);
    srow[i] = M + __logf(L);
}

// ---------------------------------------------------------------------------
// Kernel 4: pass 2, MULTI-TILE. 1024 blocks; block = (bj, 16-tile bi chunk).
// XCD k owns bj band [16k, 16k+16) (512 KB, L2-resident). B staged ONCE per
// block, then 16 tiles of {gram, exp(g-s) into LDS, contiguous 512B/wave
// float4 nontemporal stores}. LDS = B 32KB + P 34KB (no aliasing).
// ---------------------------------------------------------------------------
__global__ __launch_bounds__(256, 2) void pass2_mfma(
    const ushort* __restrict__ hHi, const ushort* __restrict__ hLo,
    const float* __restrict__ srow,
    float* __restrict__ out)
{
    const int p = blockIdx.x;
    const int xcd = p & 7, slot = p >> 3;          // slot in [0, 128)
    const int bj  = xcd * 16 + (slot & 15);        // [0, 128)
    const int bi0 = (slot >> 4) * 16;              // chunk of 16 bi tiles

    const int tid = threadIdx.x;
    const int wave = tid >> 6, lane = tid & 63;
    const int r16 = lane & 15, kb = lane >> 4;

    __shared__ __attribute__((aligned(16))) ushort sB[2 * TILE * DH];  // 32 KB
    __shared__ float ldsP[64 * S2];                                    // 34 KB

    stage_B(hHi, hLo, bj * TILE, tid, sB);
    __syncthreads();

    for (int it = 0; it < 16; ++it) {
        const int bi = bi0 + it;

        f32x4 acc[2][8];
        gram_tile(hHi, hLo, sB, bi, wave, r16, kb, acc);

#pragma unroll
        for (int hh = 0; hh < 2; ++hh) {   // 64-row half; all waves active
#pragma unroll
            for (int reg = 0; reg < 4; ++reg) {
                const int rl   = wave * 16 + kb * 4 + reg;   // row within half
                const int grow = bi * TILE + hh * 64 + rl;
                const float s  = srow[grow];
#pragma unroll
                for (int cb = 0; cb < 8; ++cb)
                    ldsP[rl * S2 + cb * 16 + r16] = __expf(acc[hh][cb][reg] - s);
            }
            __syncthreads();
            // coalesced streaming store: 2048 float4 = 64 rows x 32 float4
#pragma unroll
            for (int qq = 0; qq < 8; ++qq) {
                const int f4 = tid + 256 * qq;
                const int rl = f4 >> 5, c4 = f4 & 31;
                const f32x4 v = *(const f32x4*)&ldsP[rl * S2 + c4 * 4];
                f32x4* dst = (f32x4*)(out + (size_t)(bi * TILE + hh * 64 + rl) * N + bj * TILE + c4 * 4);
                __builtin_nontemporal_store(v, dst);
            }
            __syncthreads();   // LDS P free for next half/tile
        }
    }
}

// ---------------------------------------------------------------------------
extern "C" void kernel_launch(void* const* d_in, const int* in_sizes, int n_in,
                              void* d_out, int out_size, void* d_ws, size_t ws_size,
                              hipStream_t stream)
{
    const float* data = (const float*)d_in[0];
    const float* W1   = (const float*)d_in[1];
    const float* b1   = (const float*)d_in[2];
    const float* W2   = (const float*)d_in[3];
    const float* b2   = (const float*)d_in[4];
    const float* W3   = (const float*)d_in[5];
    const float* b3   = (const float*)d_in[6];
    float* out = (float*)d_out;

    // workspace: part_m[NT*N] | part_l[NT*N] | srow[N] | (pad N) | hHi[N*64] | hLo[N*64]
    float* part_m = (float*)d_ws;
    float* part_l = part_m + (size_t)NT * N;
    float* srow   = part_l + (size_t)NT * N;
    ushort* hHi   = (ushort*)(srow + 2 * N);
    ushort* hLo   = hHi + (size_t)N * DH;

    mlp_kernel<<<N / 128, 128, 0, stream>>>(data, W1, b1, W2, b2, W3, b3, hHi, hLo);
    pass1_mfma<<<NT * (NT + 1) / 2, 256, 0, stream>>>(hHi, hLo, part_m, part_l);
    merge_kernel<<<N / 256, 256, 0, stream>>>(part_m, part_l, srow);
    pass2_mfma<<<1024, 256, 0, stream>>>(hHi, hLo, srow, out);
}